// Round 1
// baseline (321.338 us; speedup 1.0000x reference)
//
#include <hip/hip_runtime.h>
#include <hip/hip_bf16.h>
#include <stdint.h>

#define N_TOTAL 40000
#define NROW    20000
#define D       512
#define NSAMP   25
#define KDIM    1024   // 2*D

typedef __bf16 bf16x8 __attribute__((ext_vector_type(8)));
typedef float  f32x4  __attribute__((ext_vector_type(4)));

__device__ inline float bf2f(unsigned short u) {
  union { uint32_t u; float f; } cv; cv.u = ((uint32_t)u) << 16; return cv.f;
}
__device__ inline unsigned short f2bf(float f) {
  union { float f; uint32_t u; } cv; cv.f = f;
  uint32_t u = cv.u;
  uint32_t r = (u + 0x7fffu + ((u >> 16) & 1u)) >> 16;  // RNE
  return (unsigned short)r;
}

__device__ inline void gload_lds16(const void* gsrc, void* ldst) {
  __builtin_amdgcn_global_load_lds(
      (const __attribute__((address_space(1))) uint32_t*)gsrc,
      (__attribute__((address_space(3))) uint32_t*)ldst,
      16, 0, 0);
}

// K0: convert features (f32->bf16) and W (f32->bf16)
__global__ void convert_kernel(const float* __restrict__ feat,
                               const float* __restrict__ W,
                               unsigned short* __restrict__ fbf,
                               unsigned short* __restrict__ wbf) {
  const int NF = N_TOTAL * D;      // 20,480,000
  const int NW = D * KDIM;         // 524,288
  const int total4 = (NF + NW) >> 2;
  for (int i = blockIdx.x * blockDim.x + threadIdx.x; i < total4;
       i += gridDim.x * blockDim.x) {
    int e = i << 2;
    float4 v;
    unsigned short* dst;
    if (e < NF) { v = *(const float4*)(feat + e); dst = fbf + e; }
    else        { int e2 = e - NF; v = *(const float4*)(W + e2); dst = wbf + e2; }
    ushort4 o;
    o.x = f2bf(v.x); o.y = f2bf(v.y); o.z = f2bf(v.z); o.w = f2bf(v.w);
    *(ushort4*)dst = o;
  }
}

// K1: gather self row + mean of 25 neighbor rows -> hcat bf16 [NROW][1024]
__global__ void gather_kernel(const unsigned short* __restrict__ fbf,
                              const int* __restrict__ self_idx,
                              const int* __restrict__ neigh_idx,
                              unsigned short* __restrict__ hcat) {
  const int wid = threadIdx.x >> 6;
  const int lane = threadIdx.x & 63;
  const int n = blockIdx.x * 4 + wid;
  if (n >= NROW) return;
  const int col8 = lane * 8;   // 8 bf16 per lane covers 512 cols

  int si = self_idx[n];
  si = si < 0 ? 0 : (si >= N_TOTAL ? N_TOTAL - 1 : si);
  uint4 sv = *(const uint4*)(fbf + si * D + col8);
  *(uint4*)(hcat + n * KDIM + col8) = sv;

  float acc[8];
#pragma unroll
  for (int j = 0; j < 8; ++j) acc[j] = 0.f;

#pragma unroll
  for (int s = 0; s < NSAMP; ++s) {
    int idx = neigh_idx[n * NSAMP + s];
    idx = idx < 0 ? 0 : (idx >= N_TOTAL ? N_TOTAL - 1 : idx);
    uint4 v = *(const uint4*)(fbf + idx * D + col8);
    const unsigned short* u = (const unsigned short*)&v;
#pragma unroll
    for (int j = 0; j < 8; ++j) acc[j] += bf2f(u[j]);
  }
  unsigned short ob[8];
#pragma unroll
  for (int j = 0; j < 8; ++j) ob[j] = f2bf(acc[j] * (1.0f / NSAMP));
  *(uint4*)(hcat + n * KDIM + D + col8) = *(uint4*)ob;
}

// K2: h = relu(hcat @ W^T + b), MFMA bf16, 128x128 tile, BK=32
// LDS layout (k-chunk-major): [koff 0..3][row 0..127][8 bf16]
__launch_bounds__(256)
__global__ void gemm_kernel(const unsigned short* __restrict__ hcat,
                            const unsigned short* __restrict__ wbf,
                            const float* __restrict__ bias,
                            float* __restrict__ h) {
  __shared__ unsigned short lds[8192];  // A: [0,4096), B: [4096,8192) (ushort idx)
  const int tid = threadIdx.x;
  const int lane = tid & 63, wid = tid >> 6;
  const int mb = blockIdx.x, nb = blockIdx.y;
  const int wr = wid >> 1, wc = wid & 1;

  // staging: per thread, row = tid&127, k-half = tid>>7
  const int smi = tid & 127;
  const int sk0 = tid >> 7;                 // 0/1
  int rowA = mb * 128 + smi;
  if (rowA > NROW - 1) rowA = NROW - 1;     // clamp (masked in epilogue)
  const unsigned short* gA = hcat + rowA * KDIM + sk0 * 8;
  const unsigned short* gB = wbf + (nb * 128 + smi) * KDIM + sk0 * 8;
  const int ldsWA = (wid * 1024) / 2;       // ushort index of wave dest, issue 0

  f32x4 acc[4][4];
#pragma unroll
  for (int i = 0; i < 4; ++i)
#pragma unroll
    for (int j = 0; j < 4; ++j) acc[i][j] = (f32x4){0.f, 0.f, 0.f, 0.f};

  const int koff = lane >> 4;
  const int r16 = lane & 15;

  for (int kt = 0; kt < KDIM; kt += 32) {
    gload_lds16(gA + kt,      &lds[ldsWA]);
    gload_lds16(gA + kt + 16, &lds[2048 + ldsWA]);
    gload_lds16(gB + kt,      &lds[4096 + ldsWA]);
    gload_lds16(gB + kt + 16, &lds[4096 + 2048 + ldsWA]);
    __syncthreads();

    bf16x8 af[4], bfr[4];
#pragma unroll
    for (int mf = 0; mf < 4; ++mf)
      af[mf] = *(const bf16x8*)&lds[koff * 1024 + (wr * 64 + mf * 16 + r16) * 8];
#pragma unroll
    for (int nf = 0; nf < 4; ++nf)
      bfr[nf] = *(const bf16x8*)&lds[4096 + koff * 1024 + (wc * 64 + nf * 16 + r16) * 8];
#pragma unroll
    for (int mf = 0; mf < 4; ++mf)
#pragma unroll
      for (int nf = 0; nf < 4; ++nf)
        acc[mf][nf] = __builtin_amdgcn_mfma_f32_16x16x32_bf16(
            af[mf], bfr[nf], acc[mf][nf], 0, 0, 0);
    __syncthreads();
  }

  // epilogue: C/D layout col=lane&15, row=(lane>>4)*4+reg
  const int cbase = nb * 128 + wc * 64 + r16;
  float bv[4];
#pragma unroll
  for (int nf = 0; nf < 4; ++nf) bv[nf] = bias[cbase + nf * 16];
  const int rbase = mb * 128 + wr * 64 + (lane >> 4) * 4;
#pragma unroll
  for (int mf = 0; mf < 4; ++mf) {
#pragma unroll
    for (int r = 0; r < 4; ++r) {
      const int m = rbase + mf * 16 + r;
      if (m < NROW) {
#pragma unroll
        for (int nf = 0; nf < 4; ++nf) {
          float v = acc[mf][nf][r] + bv[nf];
          v = fmaxf(v, 0.f);
          h[(long)m * D + cbase + nf * 16] = v;
        }
      }
    }
  }
}

// K3: column sum / sumsq for BN (atomics over 256 blocks)
__global__ void bnstats_kernel(const float* __restrict__ h,
                               float* __restrict__ csum,
                               float* __restrict__ csq) {
  const int c = threadIdx.x;  // 512 threads = 512 cols
  float s = 0.f, q = 0.f;
  for (int r = blockIdx.x; r < NROW; r += gridDim.x) {
    float x = h[(long)r * D + c];
    s += x; q += x * x;
  }
  atomicAdd(&csum[c], s);
  atomicAdd(&csq[c], q);
}

// K4: BN apply + row L2 normalize
__global__ void finalize_kernel(const float* __restrict__ h,
                                const float* __restrict__ csum,
                                const float* __restrict__ csq,
                                const float* __restrict__ gamma,
                                const float* __restrict__ beta,
                                float* __restrict__ out) {
  __shared__ float red[4];
  const int r = blockIdx.x;
  const int t = threadIdx.x;          // 256 threads, 2 cols each
  const int lane = t & 63, wid = t >> 6;
  float y[2];
  int cols[2] = {t, t + 256};
  float ss = 0.f;
#pragma unroll
  for (int i = 0; i < 2; ++i) {
    const int c = cols[i];
    float mu = csum[c] * (1.0f / NROW);
    float var = csq[c] * (1.0f / NROW) - mu * mu;
    var = fmaxf(var, 0.f);
    float rstd = rsqrtf(var + 1e-5f);
    float x = h[(long)r * D + c];
    y[i] = (x - mu) * rstd * gamma[c] + beta[c];
    ss += y[i] * y[i];
  }
#pragma unroll
  for (int off = 32; off > 0; off >>= 1) ss += __shfl_xor(ss, off);
  if (lane == 0) red[wid] = ss;
  __syncthreads();
  float tot = red[0] + red[1] + red[2] + red[3];
  float sc = 1.0f / (sqrtf(tot) + 1e-6f);
  out[(long)r * D + cols[0]] = y[0] * sc;
  out[(long)r * D + cols[1]] = y[1] * sc;
}

extern "C" void kernel_launch(void* const* d_in, const int* in_sizes, int n_in,
                              void* d_out, int out_size, void* d_ws, size_t ws_size,
                              hipStream_t stream) {
  const float* feat  = (const float*)d_in[0];
  const float* W     = (const float*)d_in[1];
  const float* bias  = (const float*)d_in[2];
  const float* gamma = (const float*)d_in[3];
  const float* beta  = (const float*)d_in[4];
  const int* self_idx = (const int*)d_in[5];
  const int* neigh    = (const int*)d_in[6];
  float* out = (float*)d_out;

  char* ws = (char*)d_ws;
  unsigned short* fbf  = (unsigned short*)(ws);                    // 40,960,000 B
  unsigned short* wbf  = (unsigned short*)(ws + 40960000);         //  1,048,576 B
  unsigned short* hcat = (unsigned short*)(ws + 42008576);         // 40,960,000 B
  float* h    = (float*)(ws + 82968576);                           // 40,960,000 B
  float* csum = (float*)(ws + 123928576);                          // 2048 B
  float* csq  = (float*)(ws + 123930624);                          // 2048 B

  convert_kernel<<<2048, 256, 0, stream>>>(feat, W, fbf, wbf);
  gather_kernel<<<(NROW + 3) / 4, 256, 0, stream>>>(fbf, self_idx, neigh, hcat);
  gemm_kernel<<<dim3((NROW + 127) / 128, D / 128), 256, 0, stream>>>(hcat, wbf, bias, h);
  hipMemsetAsync(csum, 0, 4096, stream);
  bnstats_kernel<<<256, 512, 0, stream>>>(h, csum, csq);
  finalize_kernel<<<NROW, 256, 0, stream>>>(h, csum, csq, gamma, beta, out);
}